// Round 12
// baseline (177.438 us; speedup 1.0000x reference)
//
#include <hip/hip_runtime.h>
#include <stdint.h>
#include <stddef.h>

typedef _Float16 f16_t;
typedef _Float16 f16x4 __attribute__((ext_vector_type(4)));
typedef _Float16 f16x8 __attribute__((ext_vector_type(8)));
typedef float f32x4 __attribute__((ext_vector_type(4)));
typedef float f32x8 __attribute__((ext_vector_type(8)));

#define AS_G __attribute__((address_space(1)))
#define AS_L __attribute__((address_space(3)))

__device__ __forceinline__ void gload_lds16(const void* g, void* l) {
  __builtin_amdgcn_global_load_lds((AS_G void*)g, (AS_L void*)l, 16, 0, 0);
}

#define FENCE() asm volatile("" ::: "memory")
#define BARX()                            \
  do {                                    \
    FENCE();                              \
    __builtin_amdgcn_s_barrier();         \
    FENCE();                              \
  } while (0)
#define VMCNT(n) asm volatile("s_waitcnt vmcnt(" #n ")" ::: "memory")

// ---------------- dispatch 1: weight prep ----------------
// blocks [0,1024): Wo f32->f16 cvt; [1024,2048): Wv transpose+cvt; [2048,3072): bconst

__global__ __launch_bounds__(256) void prep_w_kernel(
    const float* __restrict__ Wo, const float* __restrict__ Wv,
    const float* __restrict__ bv, const float* __restrict__ bo,
    const float* __restrict__ nw, int Kw,
    f16_t* __restrict__ Wo_h, f16_t* __restrict__ WvT, float* __restrict__ bc) {
  __shared__ float smem[32 * 33];
  const int b = blockIdx.x;
  const int t = threadIdx.x;
  if (b < 1024) {
    const int i = b * 256 + t;
    f32x4 v = ((const f32x4*)Wo)[i];
    f16x4 o;
    o.x = (f16_t)v.x; o.y = (f16_t)v.y; o.z = (f16_t)v.z; o.w = (f16_t)v.w;
    ((f16x4*)Wo_h)[i] = o;
  } else if (b < 2048) {
    const int i = b - 1024;
    const int bx = i & 31, by = i >> 5;
    const int tx = t & 31, ty = t >> 5;
#pragma unroll
    for (int k = 0; k < 32; k += 8)
      smem[(ty + k) * 33 + tx] = Wv[(size_t)(by * 32 + ty + k) * 1024 + bx * 32 + tx];
    __syncthreads();
#pragma unroll
    for (int k = 0; k < 32; k += 8)
      WvT[(size_t)(bx * 32 + ty + k) * 1024 + by * 32 + tx] = (f16_t)smem[tx * 33 + ty + k];
  } else {
    const int e = b - 2048;
    float sw = 0.f;
    for (int k = 0; k < Kw; ++k) sw += nw[k];
    float p = 0.f;
    for (int d = t; d < 1024; d += 256) p += Wo[(size_t)e * 1024 + d] * bv[d];
    smem[t] = p;
    __syncthreads();
    for (int s = 128; s > 0; s >>= 1) {
      if (t < s) smem[t] += smem[t + s];
      __syncthreads();
    }
    if (t == 0) bc[e] = sw * smem[0] + bo[e];
  }
}

// ---------------- dispatch 2: 128^2 GEMM (WcT = Wo_h @ WvT^T) ----------------

template <typename OutT, bool BIAS>
__global__ __launch_bounds__(256) void gemm_bt_kernel(const f16_t* __restrict__ A,
                                                      const f16_t* __restrict__ Bt,
                                                      OutT* __restrict__ C,
                                                      const float* __restrict__ bias,
                                                      int M, int N, int K) {
  __shared__ __align__(16) f16_t sA[128 * 32];
  __shared__ __align__(16) f16_t sB[128 * 32];
  const int tid = threadIdx.x;
  const int l = tid & 63;
  const int w = tid >> 6;
  const int wr = w >> 1;
  const int wc = w & 1;
  const int nMT = M >> 7;
  const int bid = blockIdx.x;
  const int mt = bid % nMT;
  const int nt = bid / nMT;
  const int m0 = mt << 7;
  const int n0 = nt << 7;

  const int srow = (w << 4) + (l >> 2);
  const int scol = (l & 3) << 3;
  const size_t aoff0 = (size_t)(m0 + srow) * K + scol;
  const size_t boff0 = (size_t)(n0 + srow) * K + scol;
  f16_t* ldsA = sA + (w << 9);
  f16_t* ldsB = sB + (w << 9);

  f32x4 acc[4][4];
#pragma unroll
  for (int i = 0; i < 4; ++i)
#pragma unroll
    for (int j = 0; j < 4; ++j) acc[i][j] = f32x4{0.f, 0.f, 0.f, 0.f};

  const int ka = (l >> 4) << 3;
  const int ar = (wr << 6) + (l & 15);
  const int br = (wc << 6) + (l & 15);

  const int nK = K >> 5;
  for (int kt = 0; kt < nK; ++kt) {
    const int kb = kt << 5;
    gload_lds16(A + aoff0 + kb, ldsA);
    gload_lds16(A + aoff0 + ((size_t)K << 6) + kb, ldsA + 2048);
    gload_lds16(Bt + boff0 + kb, ldsB);
    gload_lds16(Bt + boff0 + ((size_t)K << 6) + kb, ldsB + 2048);
    __syncthreads();
    f16x8 af[4], bfr[4];
#pragma unroll
    for (int m = 0; m < 4; ++m) af[m] = *(const f16x8*)(sA + ((ar + (m << 4)) << 5) + ka);
#pragma unroll
    for (int n = 0; n < 4; ++n) bfr[n] = *(const f16x8*)(sB + ((br + (n << 4)) << 5) + ka);
#pragma unroll
    for (int m = 0; m < 4; ++m)
#pragma unroll
      for (int n = 0; n < 4; ++n)
        acc[m][n] = __builtin_amdgcn_mfma_f32_16x16x32_f16(af[m], bfr[n], acc[m][n], 0, 0, 0);
    __syncthreads();
  }

  const int orow = (l >> 4) << 2;
  const int ocol = l & 15;
#pragma unroll
  for (int n = 0; n < 4; ++n) {
    const int gn = n0 + (wc << 6) + (n << 4) + ocol;
    const float bs = BIAS ? bias[gn] : 0.f;
#pragma unroll
    for (int m = 0; m < 4; ++m) {
      const int gm = m0 + (wr << 6) + (m << 4) + orow;
#pragma unroll
      for (int j = 0; j < 4; ++j) {
        C[(size_t)(gm + j) * N + gn] = (OutT)(acc[m][n][j] + bs);
      }
    }
  }
}

// ---------------- dispatch 3: fused G-GEMM with epilogue 3-tap ----------------
// out = S·(x@Wc) + bc, S = replicate-padded 3-tap along M.
// 256x256 out-tile, 8 waves (2Mx4N). Each wave computes NINE 16-row G-frags
// covering G rows [wr*128-1, wr*128+143] (halo for the tap), BK=32, 32 K-steps.
// A = raw f32 x staged via gload_lds into [320][32] f32 tiles (rows m0-32..m0+287,
// row index clamped to the batch -> replicate semantics), ring-2 (2x40 KB).
// B = WcT f16, proven swizzled path, ring-3 (3x16 KB). Total LDS = 128 KB.
// A-frags JIT: ds_read f32x8 (chunk32 XOR q^(row&3), both sides) + cvt to f16x8.
// Per step: issue stageA(t+1) 5x + stageB(t+2) 2x; reads; 36 MFMA; VMCNT(2)
// certifies A(t+1)+B(t+1), leaves B(t+2) flying; 1 barrier. Tails clamped.
// Epilogue: out[j'] = w0*G[j'-1..]+..: lane-local acc + one select+shfl(l+16) pair
// per (m,n) supplies the 2 cross-subblock G values (q=3 wraps to frag m+1 via
// the q==0 select trick). Verified mapping: C/D row = q*4+j, col = lr.

__device__ __forceinline__ void stageA_x(const float* __restrict__ X, int m0, int bb,
                                         int be, char* Abuf, int kt, int w, int l) {
#pragma unroll
  for (int i = 0; i < 5; ++i) {
    const int f = i * 512 + w * 64 + l;
    const int row = f >> 3;          // 0..319
    const int c = f & 7;             // 16B chunk within 128B row
    int g = m0 - 32 + row;
    g = g < bb ? bb : (g > be ? be : g);
    const int col = (kt << 5) + (((c >> 1) ^ (row & 3)) << 3) + ((c & 1) << 2);
    gload_lds16(X + (size_t)g * 1024 + col, Abuf + i * 8192 + w * 1024);
  }
}

__device__ __forceinline__ void stageB_w(const f16_t* __restrict__ Bt, int n0,
                                         char* Bgran, int kt, int w, int l) {
#pragma unroll
  for (int i = 0; i < 2; ++i) {
    const int f = i * 512 + w * 64 + l;
    const int row = f >> 2;          // 0..255
    const int ch = (f & 3) ^ ((row >> 1) & 3);
    gload_lds16(Bt + (size_t)(n0 + row) * 1024 + (kt << 5) + (ch << 3),
                Bgran + i * 8192 + w * 1024);
  }
}

__global__ __launch_bounds__(512, 2) void gemm_fused_g_kernel(
    const float* __restrict__ X, const f16_t* __restrict__ Bt,
    float* __restrict__ C, const float* __restrict__ bias,
    const float* __restrict__ nw) {
  constexpr int N = 1024, T = 4096;
  constexpr int nK = 32;
  __shared__ __align__(32) char lds[131072];  // A: 2x40960 @0; B: 3x16384 @81920

  const int tid = threadIdx.x;
  const int l = tid & 63;
  const int w = tid >> 6;
  const int wr = w >> 2;
  const int wc = w & 3;
  const int lr = l & 15;
  const int q = l >> 4;

  const int cpx = (int)gridDim.x >> 3;
  const int swzb = ((int)blockIdx.x & 7) * cpx + ((int)blockIdx.x >> 3);
  const int nNT = N >> 8;  // 4
  const int mt = swzb / nNT;
  const int nt = swzb % nNT;
  const int m0 = mt << 8;
  const int n0 = nt << 8;
  const int bb = (m0 >> 12) << 12;       // batch base (T=4096)
  const int be = bb + T - 1;

  // A frag addressing: lds_row = wr*128 + 31 + 16m + lr; (lds_row&3) const per lane
  const int rowbase = (wr << 7) + 31 + lr;
  const int axor = ((q ^ (rowbase & 3)) << 5);        // byte offset of 32B chunk
  const int bxor = ((q ^ ((lr >> 1) & 3)) << 4);      // B swizzled 16B offset
  const int brow = (wc << 6) + lr;                    // + n*16

  f32x4 acc[9][4];
#pragma unroll
  for (int m = 0; m < 9; ++m)
#pragma unroll
    for (int n = 0; n < 4; ++n) acc[m][n] = f32x4{0.f, 0.f, 0.f, 0.f};

  // prologue: A(0) -> buf0; B(0),B(1) -> gran0,1
  stageA_x(X, m0, bb, be, lds, 0, w, l);
  stageB_w(Bt, n0, lds + 81920, 0, w, l);
  stageB_w(Bt, n0, lds + 81920 + 16384, 1, w, l);
  VMCNT(0);
  BARX();

  for (int t = 0; t < nK; ++t) {
    // issue next stages (clamped at tail; uniform 7 vmem/step)
    {
      const int ka = (t + 1) < nK ? (t + 1) : (nK - 1);
      stageA_x(X, m0, bb, be, lds + ((t + 1) & 1) * 40960, ka, w, l);
      const int kb = (t + 2) < nK ? (t + 2) : (nK - 1);
      stageB_w(Bt, n0, lds + 81920 + ((t + 2) % 3) * 16384, kb, w, l);
    }

    const char* Ac = lds + (t & 1) * 40960;
    const char* Bc = lds + 81920 + (t % 3) * 16384;

    f16x8 bf[4];
#pragma unroll
    for (int n = 0; n < 4; ++n)
      bf[n] = *(const f16x8*)(Bc + ((brow + (n << 4)) << 6) + bxor);

    __builtin_amdgcn_s_setprio(1);
#pragma unroll
    for (int m = 0; m < 9; ++m) {
      f32x8 av = *(const f32x8*)(Ac + ((rowbase + (m << 4)) << 7) + axor);
      f16x8 am;
#pragma unroll
      for (int e = 0; e < 8; ++e) am[e] = (f16_t)av[e];
#pragma unroll
      for (int n = 0; n < 4; ++n)
        acc[m][n] = __builtin_amdgcn_mfma_f32_16x16x32_f16(am, bf[n], acc[m][n], 0, 0, 0);
    }
    __builtin_amdgcn_s_setprio(0);

    VMCNT(2);  // A(t+1) + B(t+1) landed; B(t+2) flying
    BARX();
  }

  // ---- epilogue: 3-tap on G + bias + store ----
  const float w0 = nw[0], w1 = nw[1], w2 = nw[2];
  const int lswap = (l + 16) & 63;
  float bs[4];
#pragma unroll
  for (int n = 0; n < 4; ++n) bs[n] = bias[n0 + (wc << 6) + (n << 4) + lr];

#pragma unroll
  for (int m = 0; m < 8; ++m) {
    const int gm = m0 + (wr << 7) + (m << 4) + (q << 2);
#pragma unroll
    for (int n = 0; n < 4; ++n) {
      // cross-subblock G values: next q's j=0,1 (or frag m+1 for q==3 via q==0 select)
      const float sel0 = (q == 0) ? acc[m + 1][n][0] : acc[m][n][0];
      const float sel1 = (q == 0) ? acc[m + 1][n][1] : acc[m][n][1];
      const float s0 = __shfl(sel0, lswap, 64);
      const float s1 = __shfl(sel1, lswap, 64);
      const float a0 = acc[m][n][0], a1 = acc[m][n][1];
      const float a2 = acc[m][n][2], a3 = acc[m][n][3];
      const int gn = n0 + (wc << 6) + (n << 4) + lr;
      float* Ccol = C + (size_t)gm * N + gn;
      Ccol[0]            = w0 * a0 + w1 * a1 + w2 * a2 + bs[n];
      Ccol[(size_t)N]    = w0 * a1 + w1 * a2 + w2 * a3 + bs[n];
      Ccol[(size_t)N*2]  = w0 * a2 + w1 * a3 + w2 * s0 + bs[n];
      Ccol[(size_t)N*3]  = w0 * a3 + w1 * s0 + w2 * s1 + bs[n];
    }
  }
}

// ---------------- launch ----------------

extern "C" void kernel_launch(void* const* d_in, const int* in_sizes, int n_in,
                              void* d_out, int out_size, void* d_ws, size_t ws_size,
                              hipStream_t stream) {
  const float* x = (const float*)d_in[0];    // [8,4096,1024]
  const float* Wv = (const float*)d_in[1];   // [1024,1024]
  const float* bv = (const float*)d_in[2];   // [1024]
  const float* Wo = (const float*)d_in[3];   // [1024,1024]
  const float* bo = (const float*)d_in[4];   // [1024]
  const float* nw = (const float*)d_in[5];   // [3]
  float* out = (float*)d_out;

  char* ws = (char*)d_ws;
  f16_t* Wo_h = (f16_t*)(ws);                  // 2 MB
  f16_t* WvT  = (f16_t*)(ws + (2u << 20));     // 2 MB
  f16_t* WcT  = (f16_t*)(ws + (4u << 20));     // 2 MB (WcT = Wo @ Wv, [e][c])
  float* bc   = (float*)(ws + (6u << 20));     // 4 KB

  // 1) weight prep
  prep_w_kernel<<<dim3(3072), dim3(256), 0, stream>>>(
      Wo, Wv, bv, bo, nw, in_sizes[5], Wo_h, WvT, bc);
  // 2) WcT[e][c] = sum_d Wo[e][d] * WvT[c][d]
  gemm_bt_kernel<f16_t, false><<<dim3(64), dim3(256), 0, stream>>>(
      Wo_h, WvT, WcT, (const float*)nullptr, 1024, 1024, 1024);
  // 3) fused: G = x@WcT^T computed with M-halo; out = 3-tap(G) + bc
  gemm_fused_g_kernel<<<dim3(512), dim3(512), 0, stream>>>(
      x, WcT, out, bc, nw);
}

// Round 13
// 161.446 us; speedup vs baseline: 1.0991x; 1.0991x over previous
//
#include <hip/hip_runtime.h>
#include <stdint.h>
#include <stddef.h>

typedef _Float16 f16_t;
typedef _Float16 f16x4 __attribute__((ext_vector_type(4)));
typedef _Float16 f16x8 __attribute__((ext_vector_type(8)));
typedef float f32x4 __attribute__((ext_vector_type(4)));
typedef float f32x8 __attribute__((ext_vector_type(8)));

#define AS_G __attribute__((address_space(1)))
#define AS_L __attribute__((address_space(3)))

__device__ __forceinline__ void gload_lds16(const void* g, void* l) {
  __builtin_amdgcn_global_load_lds((AS_G void*)g, (AS_L void*)l, 16, 0, 0);
}

#define FENCE() asm volatile("" ::: "memory")
#define BARX()                            \
  do {                                    \
    FENCE();                              \
    __builtin_amdgcn_s_barrier();         \
    FENCE();                              \
  } while (0)
#define VMCNT(n) asm volatile("s_waitcnt vmcnt(" #n ")" ::: "memory")

// ---------------- dispatch 1: fully-parallel prep ----------------
// blocks [0,4096):      xavg 3-tap (8 rows/block, f16x8 stores)
// blocks [4096,4160):   WcT = Wo @ Wv from RAW f32 (128^2 MFMA tile, LDS transpose)
// blocks [4160,5184):   bconst[e] = (sum w)*dot(Wo[e,:],bv) + bo[e]
// All branches read only kernel inputs -> single dispatch, no ordering needed.

__global__ __launch_bounds__(256) void prep_fused_kernel(
    const float* __restrict__ X, const float* __restrict__ Wo,
    const float* __restrict__ Wv, const float* __restrict__ bv,
    const float* __restrict__ bo, const float* __restrict__ nw, int Kw,
    f16_t* __restrict__ Xavg, f16_t* __restrict__ WcT, float* __restrict__ bc) {
  __shared__ __align__(16) f16_t sA[128 * 32];     // 8 KB  (wct)
  __shared__ __align__(16) float sWv[32 * 132];    // 16.9 KB (wct, padded transpose tile)
  __shared__ float smem[256];                      // 1 KB  (bconst)
  const int b = blockIdx.x;
  const int tid = threadIdx.x;

  if (b < 4096) {
    // ---- xavg: out rows [base, base+8), 2 rows/pass, f16x8 (16B) stores ----
    const int T = 4096, D = 1024;
    const int base = b * 8;
    const int bb = (base >> 12) << 12;   // batch start (T = 4096)
    const int be = bb + T - 1;           // batch end
    const int half = tid >> 7;           // 0/1: which row of the pair
    const int c8 = (tid & 127) * 8;      // 8-col chunk
    const float w0 = nw[0], w1 = nw[1], w2 = nw[2];
#pragma unroll
    for (int g = 0; g < 4; ++g) {
      const int r = base + 2 * g + half;
      const int rm = (r > bb) ? r - 1 : bb;
      const int rp = (r < be) ? r + 1 : be;
      f32x8 a = *(const f32x8*)(X + (size_t)rm * D + c8);
      f32x8 v = *(const f32x8*)(X + (size_t)r * D + c8);
      f32x8 c = *(const f32x8*)(X + (size_t)rp * D + c8);
      f32x8 y = w0 * a + w1 * v + w2 * c;
      f16x8 o;
#pragma unroll
      for (int e = 0; e < 8; ++e) o[e] = (f16_t)y[e];
      *(f16x8*)(Xavg + (size_t)r * D + c8) = o;
    }
  } else if (b < 4160) {
    // ---- WcT[e][c] = sum_d Wo[e][d]*Wv[d][c], f32 inputs, f16 out ----
    constexpr int K = 1024, NN = 1024;
    const int bid = b - 4096;
    const int mt = bid & 7, nt = bid >> 3;
    const int m0 = mt << 7, n0 = nt << 7;
    const int l = tid & 63, w = tid >> 6;
    const int wr = w >> 1, wc = w & 1;
    const int ka = (l >> 4) << 3;
    const int ar = (wr << 6) + (l & 15);
    const int br = (wc << 6) + (l & 15);

    f32x4 acc[4][4];
#pragma unroll
    for (int i = 0; i < 4; ++i)
#pragma unroll
      for (int j = 0; j < 4; ++j) acc[i][j] = f32x4{0.f, 0.f, 0.f, 0.f};

    for (int kt = 0; kt < (K >> 5); ++kt) {
      const int kb = kt << 5;
      // A: Wo rows m0..m0+127, cols kb..kb+31, cvt f32->f16
#pragma unroll
      for (int i = 0; i < 2; ++i) {
        const int u = tid + i * 256;
        const int row = u >> 2, ch = u & 3;
        f32x8 v = *(const f32x8*)(Wo + (size_t)(m0 + row) * K + kb + ch * 8);
        f16x8 h;
#pragma unroll
        for (int e = 0; e < 8; ++e) h[e] = (f16_t)v[e];
        *(f16x8*)(sA + row * 32 + ch * 8) = h;
      }
      // B: Wv rows kb..kb+31, cols n0..n0+127 -> padded f32 tile [k][132]
#pragma unroll
      for (int i = 0; i < 4; ++i) {
        const int u = tid + i * 256;
        const int k = u >> 5, c4 = u & 31;
        f32x4 v = *(const f32x4*)(Wv + (size_t)(kb + k) * NN + n0 + c4 * 4);
        *(f32x4*)(sWv + k * 132 + c4 * 4) = v;
      }
      __syncthreads();
      f16x8 af[4], bfr[4];
#pragma unroll
      for (int m = 0; m < 4; ++m) af[m] = *(const f16x8*)(sA + (ar + (m << 4)) * 32 + ka);
#pragma unroll
      for (int n = 0; n < 4; ++n) {
#pragma unroll
        for (int e = 0; e < 8; ++e)
          bfr[n][e] = (f16_t)sWv[(ka + e) * 132 + br + (n << 4)];
      }
#pragma unroll
      for (int m = 0; m < 4; ++m)
#pragma unroll
        for (int n = 0; n < 4; ++n)
          acc[m][n] = __builtin_amdgcn_mfma_f32_16x16x32_f16(af[m], bfr[n], acc[m][n], 0, 0, 0);
      __syncthreads();
    }

    const int orow = (l >> 4) << 2;
    const int ocol = l & 15;
#pragma unroll
    for (int n = 0; n < 4; ++n) {
      const int gn = n0 + (wc << 6) + (n << 4) + ocol;
#pragma unroll
      for (int m = 0; m < 4; ++m) {
        const int gm = m0 + (wr << 6) + (m << 4) + orow;
#pragma unroll
        for (int j = 0; j < 4; ++j)
          WcT[(size_t)(gm + j) * NN + gn] = (f16_t)acc[m][n][j];
      }
    }
  } else {
    // ---- bconst ----
    const int e = b - 4160;
    float sw = 0.f;
    for (int k = 0; k < Kw; ++k) sw += nw[k];
    float p = 0.f;
    for (int d = tid; d < 1024; d += 256) p += Wo[(size_t)e * 1024 + d] * bv[d];
    smem[tid] = p;
    __syncthreads();
    for (int s = 128; s > 0; s >>= 1) {
      if (tid < s) smem[tid] += smem[tid + s];
      __syncthreads();
    }
    if (tid == 0) bc[e] = sw * smem[0] + bo[e];
  }
}

// ---------------- dispatch 2: 256^2 pipelined GEMM (round-5/11 best config) ----------------
// out[M][N] = Xavg[M][K]*WcT[N][K]^T + bc. 8 waves (2Mx4N), BK=32, 16x16x32 MFMA.
// Ring-4 LDS granules (32 KB each = 128 KB), prefetch distance 3, one counted
// VMCNT(8) + one barrier per K-step. XOR chunk swizzle both sides (0-conflict).

__device__ __forceinline__ void stage256(const f16_t* __restrict__ g, int K,
                                         f16_t* ldsOp, int w, int l) {
#pragma unroll
  for (int i = 0; i < 2; ++i) {
    const int f = i * 512 + w * 64 + l;
    const int row = f >> 2;
    const int ch = f & 3;
    const int col = (((ch ^ ((row >> 1) & 3))) << 3);
    gload_lds16(g + (size_t)row * K + col, ldsOp + i * 4096 + w * 512);
  }
}

__global__ __launch_bounds__(512, 2) void gemm256_kernel(const f16_t* __restrict__ A,
                                                         const f16_t* __restrict__ Bt,
                                                         float* __restrict__ C,
                                                         const float* __restrict__ bias,
                                                         int M, int N, int K) {
  __shared__ __align__(16) f16_t lds[4 * 16384];
  const int tid = threadIdx.x;
  const int l = tid & 63;
  const int w = tid >> 6;
  const int wr = w >> 2;
  const int wc = w & 3;
  const int lr = l & 15;
  const int q = l >> 4;

  const int cpx = (int)gridDim.x >> 3;
  const int swzb = ((int)blockIdx.x & 7) * cpx + ((int)blockIdx.x >> 3);
  const int nNT = N >> 8;
  const int mt = swzb / nNT;
  const int nt = swzb % nNT;
  const int m0 = mt << 8;
  const int n0 = nt << 8;

  const f16_t* Apanel = A + (size_t)m0 * K;
  const f16_t* Bpanel = Bt + (size_t)n0 * K;
  const int sw = (q ^ ((lr >> 1) & 3)) << 3;

  f32x4 acc[8][4];
#pragma unroll
  for (int m = 0; m < 8; ++m)
#pragma unroll
    for (int n = 0; n < 4; ++n) acc[m][n] = f32x4{0.f, 0.f, 0.f, 0.f};

  const int nK = K >> 5;

  for (int t = 0; t < 3; ++t) {
    f16_t* buf = lds + (t & 3) * 16384;
    stage256(Apanel + (t << 5), K, buf, w, l);
    stage256(Bpanel + (t << 5), K, buf + 8192, w, l);
  }
  VMCNT(8);
  BARX();

  for (int t = 0; t < nK; ++t) {
    f16_t* sA = lds + (t & 3) * 16384;
    f16_t* sB = sA + 8192;

    {
      const int tn = (t + 3) < nK ? (t + 3) : (nK - 1);
      f16_t* nbuf = lds + ((t + 3) & 3) * 16384;
      stage256(Apanel + ((size_t)tn << 5), K, nbuf, w, l);
      stage256(Bpanel + ((size_t)tn << 5), K, nbuf + 8192, w, l);
    }

    f16x8 bf[4], af[4], ag[4];
#pragma unroll
    for (int n = 0; n < 4; ++n)
      bf[n] = *(const f16x8*)(sB + (((wc << 6) + (n << 4) + lr) << 5) + sw);
#pragma unroll
    for (int m = 0; m < 4; ++m)
      af[m] = *(const f16x8*)(sA + (((wr << 7) + (m << 4) + lr) << 5) + sw);
#pragma unroll
    for (int m = 0; m < 4; ++m)
      ag[m] = *(const f16x8*)(sA + (((wr << 7) + 64 + (m << 4) + lr) << 5) + sw);

    __builtin_amdgcn_s_setprio(1);
#pragma unroll
    for (int m = 0; m < 4; ++m)
#pragma unroll
      for (int n = 0; n < 4; ++n)
        acc[m][n] = __builtin_amdgcn_mfma_f32_16x16x32_f16(af[m], bf[n], acc[m][n], 0, 0, 0);
#pragma unroll
    for (int m = 0; m < 4; ++m)
#pragma unroll
      for (int n = 0; n < 4; ++n)
        acc[m + 4][n] = __builtin_amdgcn_mfma_f32_16x16x32_f16(ag[m], bf[n], acc[m + 4][n], 0, 0, 0);
    __builtin_amdgcn_s_setprio(0);

    VMCNT(8);
    BARX();
  }

  float bs[4];
#pragma unroll
  for (int n = 0; n < 4; ++n) bs[n] = bias[n0 + (wc << 6) + (n << 4) + lr];
#pragma unroll
  for (int m = 0; m < 8; ++m) {
    const int gm = m0 + (wr << 7) + (m << 4) + (q << 2);
#pragma unroll
    for (int j = 0; j < 4; ++j) {
      float* Crow = C + (size_t)(gm + j) * N + n0 + (wc << 6) + lr;
#pragma unroll
      for (int n = 0; n < 4; ++n) Crow[n << 4] = acc[m][n][j] + bs[n];
    }
  }
}

// ---------------- launch ----------------

extern "C" void kernel_launch(void* const* d_in, const int* in_sizes, int n_in,
                              void* d_out, int out_size, void* d_ws, size_t ws_size,
                              hipStream_t stream) {
  const float* x = (const float*)d_in[0];    // [8,4096,1024]
  const float* Wv = (const float*)d_in[1];   // [1024,1024]
  const float* bv = (const float*)d_in[2];   // [1024]
  const float* Wo = (const float*)d_in[3];   // [1024,1024]
  const float* bo = (const float*)d_in[4];   // [1024]
  const float* nw = (const float*)d_in[5];   // [3]
  float* out = (float*)d_out;

  char* ws = (char*)d_ws;
  f16_t* WcT  = (f16_t*)(ws + (4u << 20));     // 2 MB (WcT = Wo @ Wv, [e][c])
  float* bc   = (float*)(ws + (6u << 20));     // 4 KB
  f16_t* Xavg = (f16_t*)(ws + (8u << 20));     // 64 MB

  // 1) fully-parallel prep: xavg || WcT-from-f32 || bconst (one dispatch)
  prep_fused_kernel<<<dim3(5184), dim3(256), 0, stream>>>(
      x, Wo, Wv, bv, bo, nw, in_sizes[5], Xavg, WcT, bc);
  // 2) out[r][e] = sum_c Xavg[r][c] * WcT[e][c] + bc[e]
  gemm256_kernel<<<dim3(512), dim3(512), 0, stream>>>(
      Xavg, WcT, out, bc, 32768, 1024, 1024);
}

// Round 14
// 145.102 us; speedup vs baseline: 1.2229x; 1.1126x over previous
//
#include <hip/hip_runtime.h>
#include <stdint.h>
#include <stddef.h>

typedef _Float16 f16_t;
typedef _Float16 f16x4 __attribute__((ext_vector_type(4)));
typedef _Float16 f16x8 __attribute__((ext_vector_type(8)));
typedef float f32x4 __attribute__((ext_vector_type(4)));
typedef float f32x8 __attribute__((ext_vector_type(8)));

#define AS_G __attribute__((address_space(1)))
#define AS_L __attribute__((address_space(3)))

__device__ __forceinline__ void gload_lds16(const void* g, void* l) {
  __builtin_amdgcn_global_load_lds((AS_G void*)g, (AS_L void*)l, 16, 0, 0);
}

#define FENCE() asm volatile("" ::: "memory")
#define BARX()                            \
  do {                                    \
    FENCE();                              \
    __builtin_amdgcn_s_barrier();         \
    FENCE();                              \
  } while (0)
#define VMCNT(n) asm volatile("s_waitcnt vmcnt(" #n ")" ::: "memory")

// ---------------- dispatch 1: fully-parallel prep (ordered for co-run) ----------------
// blocks [0,64):        WcT = Wo @ Wv from RAW f32 (128^2 MFMA; LDS write-transpose)
// blocks [64,1088):     bconst[e] = (sum w)*dot(Wo[e,:],bv) + bo[e]
// blocks [1088,5184):   xavg 3-tap (8 rows/block, rolling registers)
// WcT blocks dispatch FIRST -> hidden under the memory-bound xavg flood.

__global__ __launch_bounds__(256) void prep_fused_kernel(
    const float* __restrict__ X, const float* __restrict__ Wo,
    const float* __restrict__ Wv, const float* __restrict__ bv,
    const float* __restrict__ bo, const float* __restrict__ nw, int Kw,
    f16_t* __restrict__ Xavg, f16_t* __restrict__ WcT, float* __restrict__ bc) {
  __shared__ __align__(16) f16_t sA[128 * 32];     // 8 KB   (wct A tile)
  __shared__ __align__(16) float sWvT[128 * 36];   // 18 KB  (wct B^T tile, pad 36)
  __shared__ float smem[256];                      // 1 KB   (bconst)
  const int b = blockIdx.x;
  const int tid = threadIdx.x;

  if (b < 64) {
    // ---- WcT[e][c] = sum_d Wo[e][d]*Wv[d][c], raw f32 inputs, f16 out ----
    constexpr int K = 1024, NN = 1024;
    const int mt = b & 7, nt = b >> 3;
    const int m0 = mt << 7, n0 = nt << 7;
    const int l = tid & 63, w = tid >> 6;
    const int wr = w >> 1, wc = w & 1;
    const int q = l >> 4;
    const int ka = q << 3;
    const int ar = (wr << 6) + (l & 15);
    const int br = (wc << 6) + (l & 15);
    const int kS = tid >> 3;          // staging: k row 0..31
    const int cS = (tid & 7) << 4;    // staging: c base 0..112

    f32x4 acc[4][4];
#pragma unroll
    for (int i = 0; i < 4; ++i)
#pragma unroll
      for (int j = 0; j < 4; ++j) acc[i][j] = f32x4{0.f, 0.f, 0.f, 0.f};

    for (int kt = 0; kt < (K >> 5); ++kt) {
      const int kb = kt << 5;
      // A: Wo rows m0..m0+127, cols kb..kb+31 -> f16 [row][32]
#pragma unroll
      for (int i = 0; i < 2; ++i) {
        const int u = tid + i * 256;
        const int row = u >> 2, ch = u & 3;
        f32x8 v = *(const f32x8*)(Wo + (size_t)(m0 + row) * K + kb + ch * 8);
        f16x8 h;
#pragma unroll
        for (int e = 0; e < 8; ++e) h[e] = (f16_t)v[e];
        *(f16x8*)(sA + row * 32 + ch * 8) = h;
      }
      // B: Wv rows kb..kb+31, cols n0..n0+127 -> TRANSPOSED f32 [c][k], pad 36
#pragma unroll
      for (int j = 0; j < 4; ++j) {
        f32x4 v = *(const f32x4*)(Wv + (size_t)(kb + kS) * NN + n0 + cS + 4 * j);
#pragma unroll
        for (int i = 0; i < 4; ++i) sWvT[(cS + 4 * j + i) * 36 + kS] = v[i];
      }
      __syncthreads();
      f16x8 af[4], bfr[4];
#pragma unroll
      for (int m = 0; m < 4; ++m) af[m] = *(const f16x8*)(sA + (ar + (m << 4)) * 32 + ka);
#pragma unroll
      for (int n = 0; n < 4; ++n) {
        f32x4 v0 = *(const f32x4*)(sWvT + (br + (n << 4)) * 36 + ka);
        f32x4 v1 = *(const f32x4*)(sWvT + (br + (n << 4)) * 36 + ka + 4);
#pragma unroll
        for (int e = 0; e < 4; ++e) {
          bfr[n][e] = (f16_t)v0[e];
          bfr[n][e + 4] = (f16_t)v1[e];
        }
      }
#pragma unroll
      for (int m = 0; m < 4; ++m)
#pragma unroll
        for (int n = 0; n < 4; ++n)
          acc[m][n] = __builtin_amdgcn_mfma_f32_16x16x32_f16(af[m], bfr[n], acc[m][n], 0, 0, 0);
      __syncthreads();
    }

    const int orow = q << 2;
    const int ocol = l & 15;
#pragma unroll
    for (int n = 0; n < 4; ++n) {
      const int gn = n0 + (wc << 6) + (n << 4) + ocol;
#pragma unroll
      for (int m = 0; m < 4; ++m) {
        const int gm = m0 + (wr << 6) + (m << 4) + orow;
#pragma unroll
        for (int j = 0; j < 4; ++j)
          WcT[(size_t)(gm + j) * NN + gn] = (f16_t)acc[m][n][j];
      }
    }
  } else if (b < 1088) {
    // ---- bconst ----
    const int e = b - 64;
    float sw = 0.f;
    for (int k = 0; k < Kw; ++k) sw += nw[k];
    float p = 0.f;
    for (int d = tid; d < 1024; d += 256) p += Wo[(size_t)e * 1024 + d] * bv[d];
    smem[tid] = p;
    __syncthreads();
    for (int s = 128; s > 0; s >>= 1) {
      if (tid < s) smem[tid] += smem[tid + s];
      __syncthreads();
    }
    if (tid == 0) bc[e] = sw * smem[0] + bo[e];
  } else {
    // ---- xavg: 3-tap temporal smoothing, rolling registers, fp16 out ----
    const int T = 4096, D = 1024;
    const int base = (b - 1088) * 8;
    const int t0 = base & (T - 1);
    const int col = tid * 4;
    const float w0 = nw[0], w1 = nw[1], w2 = nw[2];
    const float* xb = X + (size_t)base * D + col;
    f32x4 va = *(const f32x4*)(xb + (t0 == 0 ? 0 : -D));
    f32x4 vb = *(const f32x4*)(xb);
    f16_t* ob = Xavg + (size_t)base * D + col;
#pragma unroll
    for (int g = 0; g < 8; ++g) {
      f32x4 vc;
      if (t0 + g == T - 1) vc = vb;
      else vc = *(const f32x4*)(xb + (size_t)(g + 1) * D);
      f32x4 y = w0 * va + w1 * vb + w2 * vc;
      f16x4 o;
      o.x = (f16_t)y.x; o.y = (f16_t)y.y; o.z = (f16_t)y.z; o.w = (f16_t)y.w;
      *(f16x4*)(ob + (size_t)g * D) = o;
      va = vb;
      vb = vc;
    }
  }
}

// ---------------- dispatch 2: 256^2 pipelined GEMM (round-5/11 best config) ----------------
// out[M][N] = Xavg[M][K]*WcT[N][K]^T + bc. 8 waves (2Mx4N), BK=32, 16x16x32 MFMA.
// Ring-4 LDS granules (32 KB each = 128 KB), prefetch distance 3, one counted
// VMCNT(8) + one barrier per K-step. XOR chunk swizzle both sides (0-conflict).

__device__ __forceinline__ void stage256(const f16_t* __restrict__ g, int K,
                                         f16_t* ldsOp, int w, int l) {
#pragma unroll
  for (int i = 0; i < 2; ++i) {
    const int f = i * 512 + w * 64 + l;
    const int row = f >> 2;
    const int ch = f & 3;
    const int col = (((ch ^ ((row >> 1) & 3))) << 3);
    gload_lds16(g + (size_t)row * K + col, ldsOp + i * 4096 + w * 512);
  }
}

__global__ __launch_bounds__(512, 2) void gemm256_kernel(const f16_t* __restrict__ A,
                                                         const f16_t* __restrict__ Bt,
                                                         float* __restrict__ C,
                                                         const float* __restrict__ bias,
                                                         int M, int N, int K) {
  __shared__ __align__(16) f16_t lds[4 * 16384];
  const int tid = threadIdx.x;
  const int l = tid & 63;
  const int w = tid >> 6;
  const int wr = w >> 2;
  const int wc = w & 3;
  const int lr = l & 15;
  const int q = l >> 4;

  const int cpx = (int)gridDim.x >> 3;
  const int swzb = ((int)blockIdx.x & 7) * cpx + ((int)blockIdx.x >> 3);
  const int nNT = N >> 8;
  const int mt = swzb / nNT;
  const int nt = swzb % nNT;
  const int m0 = mt << 8;
  const int n0 = nt << 8;

  const f16_t* Apanel = A + (size_t)m0 * K;
  const f16_t* Bpanel = Bt + (size_t)n0 * K;
  const int sw = (q ^ ((lr >> 1) & 3)) << 3;

  f32x4 acc[8][4];
#pragma unroll
  for (int m = 0; m < 8; ++m)
#pragma unroll
    for (int n = 0; n < 4; ++n) acc[m][n] = f32x4{0.f, 0.f, 0.f, 0.f};

  const int nK = K >> 5;

  for (int t = 0; t < 3; ++t) {
    f16_t* buf = lds + (t & 3) * 16384;
    stage256(Apanel + (t << 5), K, buf, w, l);
    stage256(Bpanel + (t << 5), K, buf + 8192, w, l);
  }
  VMCNT(8);
  BARX();

  for (int t = 0; t < nK; ++t) {
    f16_t* sA = lds + (t & 3) * 16384;
    f16_t* sB = sA + 8192;

    {
      const int tn = (t + 3) < nK ? (t + 3) : (nK - 1);
      f16_t* nbuf = lds + ((t + 3) & 3) * 16384;
      stage256(Apanel + ((size_t)tn << 5), K, nbuf, w, l);
      stage256(Bpanel + ((size_t)tn << 5), K, nbuf + 8192, w, l);
    }

    f16x8 bf[4], af[4], ag[4];
#pragma unroll
    for (int n = 0; n < 4; ++n)
      bf[n] = *(const f16x8*)(sB + (((wc << 6) + (n << 4) + lr) << 5) + sw);
#pragma unroll
    for (int m = 0; m < 4; ++m)
      af[m] = *(const f16x8*)(sA + (((wr << 7) + (m << 4) + lr) << 5) + sw);
#pragma unroll
    for (int m = 0; m < 4; ++m)
      ag[m] = *(const f16x8*)(sA + (((wr << 7) + 64 + (m << 4) + lr) << 5) + sw);

    __builtin_amdgcn_s_setprio(1);
#pragma unroll
    for (int m = 0; m < 4; ++m)
#pragma unroll
      for (int n = 0; n < 4; ++n)
        acc[m][n] = __builtin_amdgcn_mfma_f32_16x16x32_f16(af[m], bf[n], acc[m][n], 0, 0, 0);
#pragma unroll
    for (int m = 0; m < 4; ++m)
#pragma unroll
      for (int n = 0; n < 4; ++n)
        acc[m + 4][n] = __builtin_amdgcn_mfma_f32_16x16x32_f16(ag[m], bf[n], acc[m + 4][n], 0, 0, 0);
    __builtin_amdgcn_s_setprio(0);

    VMCNT(8);
    BARX();
  }

  float bs[4];
#pragma unroll
  for (int n = 0; n < 4; ++n) bs[n] = bias[n0 + (wc << 6) + (n << 4) + lr];
#pragma unroll
  for (int m = 0; m < 8; ++m) {
    const int gm = m0 + (wr << 7) + (m << 4) + (q << 2);
#pragma unroll
    for (int j = 0; j < 4; ++j) {
      float* Crow = C + (size_t)(gm + j) * N + n0 + (wc << 6) + lr;
#pragma unroll
      for (int n = 0; n < 4; ++n) Crow[n << 4] = acc[m][n][j] + bs[n];
    }
  }
}

// ---------------- launch ----------------

extern "C" void kernel_launch(void* const* d_in, const int* in_sizes, int n_in,
                              void* d_out, int out_size, void* d_ws, size_t ws_size,
                              hipStream_t stream) {
  const float* x = (const float*)d_in[0];    // [8,4096,1024]
  const float* Wv = (const float*)d_in[1];   // [1024,1024]
  const float* bv = (const float*)d_in[2];   // [1024]
  const float* Wo = (const float*)d_in[3];   // [1024,1024]
  const float* bo = (const float*)d_in[4];   // [1024]
  const float* nw = (const float*)d_in[5];   // [3]
  float* out = (float*)d_out;

  char* ws = (char*)d_ws;
  f16_t* WcT  = (f16_t*)(ws + (4u << 20));     // 2 MB (WcT = Wo @ Wv, [e][c])
  float* bc   = (float*)(ws + (6u << 20));     // 4 KB
  f16_t* Xavg = (f16_t*)(ws + (8u << 20));     // 64 MB

  // 1) parallel prep: WcT (first, hidden) || bconst || xavg
  prep_fused_kernel<<<dim3(5184), dim3(256), 0, stream>>>(
      x, Wo, Wv, bv, bo, nw, in_sizes[5], Xavg, WcT, bc);
  // 2) out[r][e] = sum_c Xavg[r][c] * WcT[e][c] + bc[e]
  gemm256_kernel<<<dim3(512), dim3(512), 0, stream>>>(
      Xavg, WcT, out, bc, 32768, 1024, 1024);
}

// Round 15
// 140.981 us; speedup vs baseline: 1.2586x; 1.0292x over previous
//
#include <hip/hip_runtime.h>
#include <stdint.h>
#include <stddef.h>

typedef _Float16 f16_t;
typedef _Float16 f16x4 __attribute__((ext_vector_type(4)));
typedef _Float16 f16x8 __attribute__((ext_vector_type(8)));
typedef float f32x4 __attribute__((ext_vector_type(4)));
typedef float f32x8 __attribute__((ext_vector_type(8)));

#define AS_G __attribute__((address_space(1)))
#define AS_L __attribute__((address_space(3)))

__device__ __forceinline__ void gload_lds16(const void* g, void* l) {
  __builtin_amdgcn_global_load_lds((AS_G void*)g, (AS_L void*)l, 16, 0, 0);
}

#define FENCE() asm volatile("" ::: "memory")
#define BARX()                            \
  do {                                    \
    FENCE();                              \
    __builtin_amdgcn_s_barrier();         \
    FENCE();                              \
  } while (0)
#define VMCNT(n) asm volatile("s_waitcnt vmcnt(" #n ")" ::: "memory")
#define LGKM0() asm volatile("s_waitcnt lgkmcnt(0)" ::: "memory")
#if defined(__HIP_DEVICE_COMPILE__)
#define SCHEDB0() __builtin_amdgcn_sched_barrier(0)
#else
#define SCHEDB0()
#endif

// ---------------- dispatch 1: fully-parallel prep (r14-proven) ----------------
// blocks [0,64): WcT from raw f32; [64,1088): bconst; [1088,5184): xavg 3-tap.

__global__ __launch_bounds__(256) void prep_fused_kernel(
    const float* __restrict__ X, const float* __restrict__ Wo,
    const float* __restrict__ Wv, const float* __restrict__ bv,
    const float* __restrict__ bo, const float* __restrict__ nw, int Kw,
    f16_t* __restrict__ Xavg, f16_t* __restrict__ WcT, float* __restrict__ bc) {
  __shared__ __align__(16) f16_t sA[128 * 32];
  __shared__ __align__(16) float sWvT[128 * 36];
  __shared__ float smem[256];
  const int b = blockIdx.x;
  const int tid = threadIdx.x;

  if (b < 64) {
    constexpr int K = 1024, NN = 1024;
    const int mt = b & 7, nt = b >> 3;
    const int m0 = mt << 7, n0 = nt << 7;
    const int l = tid & 63, w = tid >> 6;
    const int wr = w >> 1, wc = w & 1;
    const int q = l >> 4;
    const int ka = q << 3;
    const int ar = (wr << 6) + (l & 15);
    const int br = (wc << 6) + (l & 15);
    const int kS = tid >> 3;
    const int cS = (tid & 7) << 4;

    f32x4 acc[4][4];
#pragma unroll
    for (int i = 0; i < 4; ++i)
#pragma unroll
      for (int j = 0; j < 4; ++j) acc[i][j] = f32x4{0.f, 0.f, 0.f, 0.f};

    for (int kt = 0; kt < (K >> 5); ++kt) {
      const int kb = kt << 5;
#pragma unroll
      for (int i = 0; i < 2; ++i) {
        const int u = tid + i * 256;
        const int row = u >> 2, ch = u & 3;
        f32x8 v = *(const f32x8*)(Wo + (size_t)(m0 + row) * K + kb + ch * 8);
        f16x8 h;
#pragma unroll
        for (int e = 0; e < 8; ++e) h[e] = (f16_t)v[e];
        *(f16x8*)(sA + row * 32 + ch * 8) = h;
      }
#pragma unroll
      for (int j = 0; j < 4; ++j) {
        f32x4 v = *(const f32x4*)(Wv + (size_t)(kb + kS) * NN + n0 + cS + 4 * j);
#pragma unroll
        for (int i = 0; i < 4; ++i) sWvT[(cS + 4 * j + i) * 36 + kS] = v[i];
      }
      __syncthreads();
      f16x8 af[4], bfr[4];
#pragma unroll
      for (int m = 0; m < 4; ++m) af[m] = *(const f16x8*)(sA + (ar + (m << 4)) * 32 + ka);
#pragma unroll
      for (int n = 0; n < 4; ++n) {
        f32x4 v0 = *(const f32x4*)(sWvT + (br + (n << 4)) * 36 + ka);
        f32x4 v1 = *(const f32x4*)(sWvT + (br + (n << 4)) * 36 + ka + 4);
#pragma unroll
        for (int e = 0; e < 4; ++e) {
          bfr[n][e] = (f16_t)v0[e];
          bfr[n][e + 4] = (f16_t)v1[e];
        }
      }
#pragma unroll
      for (int m = 0; m < 4; ++m)
#pragma unroll
        for (int n = 0; n < 4; ++n)
          acc[m][n] = __builtin_amdgcn_mfma_f32_16x16x32_f16(af[m], bfr[n], acc[m][n], 0, 0, 0);
      __syncthreads();
    }

    const int orow = q << 2;
    const int ocol = l & 15;
#pragma unroll
    for (int n = 0; n < 4; ++n) {
      const int gn = n0 + (wc << 6) + (n << 4) + ocol;
#pragma unroll
      for (int m = 0; m < 4; ++m) {
        const int gm = m0 + (wr << 6) + (m << 4) + orow;
#pragma unroll
        for (int j = 0; j < 4; ++j)
          WcT[(size_t)(gm + j) * NN + gn] = (f16_t)acc[m][n][j];
      }
    }
  } else if (b < 1088) {
    const int e = b - 64;
    float sw = 0.f;
    for (int k = 0; k < Kw; ++k) sw += nw[k];
    float p = 0.f;
    for (int d = tid; d < 1024; d += 256) p += Wo[(size_t)e * 1024 + d] * bv[d];
    smem[tid] = p;
    __syncthreads();
    for (int s = 128; s > 0; s >>= 1) {
      if (tid < s) smem[tid] += smem[tid + s];
      __syncthreads();
    }
    if (tid == 0) bc[e] = sw * smem[0] + bo[e];
  } else {
    const int T = 4096, D = 1024;
    const int base = (b - 1088) * 8;
    const int t0 = base & (T - 1);
    const int col = tid * 4;
    const float w0 = nw[0], w1 = nw[1], w2 = nw[2];
    const float* xb = X + (size_t)base * D + col;
    f32x4 va = *(const f32x4*)(xb + (t0 == 0 ? 0 : -D));
    f32x4 vb = *(const f32x4*)(xb);
    f16_t* ob = Xavg + (size_t)base * D + col;
#pragma unroll
    for (int g = 0; g < 8; ++g) {
      f32x4 vc;
      if (t0 + g == T - 1) vc = vb;
      else vc = *(const f32x4*)(xb + (size_t)(g + 1) * D);
      f32x4 y = w0 * va + w1 * vb + w2 * vc;
      f16x4 o;
      o.x = (f16_t)y.x; o.y = (f16_t)y.y; o.z = (f16_t)y.z; o.w = (f16_t)y.w;
      *(f16x4*)(ob + (size_t)g * D) = o;
      va = vb;
      vb = vc;
    }
  }
}

// ---------------- dispatch 2: 256^2 GEMM, m201-faithful 8-phase + counted vmcnt ----------------
// out[M][N] = A[M][K]*Bt[N][K]^T + bias. 8 waves (2Mx4N), 16x16x32 MFMA, BK=64.
// LDS: 2 bufs x (A 32KB + B 32KB). Chunk layouts reordered so phase needs are
// issue-order prefixes: A = [mhalf][wr][64r][64c], B = [npair][wc][32r][64c].
// Per tile: ph0 {read a0(8)+b0(4); stage A0,B0; VMCNT(2); BAR; LGKM0; 16 MFMA; BAR}
//           ph1 {read b1(4); stage A1,B1; BAR; LGKM0; 16 MFMA; BAR}
//           ph2 {read a1(8); stage A2,B2; BAR; LGKM0; 16 MFMA; BAR}
//           ph3 {stage A3,B3; BAR; 16 MFMA; VMCNT(4); BAR}
// Wait proof (steady state, issue order A0,B0,A1,B1,A2,B2,A3,B3 per tile):
//   tile start: outstanding = [A2,B2,A3,B3] (this tile's ph1/ph2 frag sources).
//   ph0 VMCNT(2)+BAR certifies them before ph1/ph2's ds_reads (leaves A0',B0').
//   ph3 VMCNT(4)+BAR: outstanding [A0'..B3'] (8) -> drains A0',B0',A1',B1' =
//   next tile's ph0 needs; leaves [A2',B2',A3',B3'] = invariant. Never vmcnt(0).
// Buffer hazard: stages write buf[(tt+1)&1], whose old content (tile tt-1) was
// fully consumed before this tile's first barrier. Tail clamps restage tile nT-1
// (dead writes, uniform counts). XOR row swizzle both sides (2-way, free).

__device__ __forceinline__ void stageA64(const f16_t* __restrict__ Ap, int K, int kt,
                                         int c, char* bufA, int w, int l) {
  const int f = w * 64 + l;
  const int sub = f >> 3, ch = f & 7;
  const int grow = ((c & 1) << 7) + ((c >> 1) << 6) + sub;   // [mh][wr] chunk order
  const int gcol = (kt << 6) + ((ch ^ (sub & 7)) << 3);
  gload_lds16(Ap + (size_t)grow * K + gcol, bufA + c * 8192 + w * 1024);
}

__device__ __forceinline__ void stageB64(const f16_t* __restrict__ Bp, int K, int kt,
                                         int c, char* bufB, int w, int l) {
  const int f = w * 64 + l;
  const int rr = f >> 3, ch = f & 7;
  const int wc = ((c & 1) << 1) + (rr >> 5);                 // [np][wcpair] chunk order
  const int sub = rr & 31;
  const int grow = (wc << 6) + ((c >> 1) << 5) + sub;
  const int gcol = (kt << 6) + ((ch ^ (sub & 7)) << 3);
  gload_lds16(Bp + (size_t)grow * K + gcol, bufB + c * 8192 + w * 1024);
}

__global__ __launch_bounds__(512, 2) void gemm8p_kernel(const f16_t* __restrict__ A,
                                                        const f16_t* __restrict__ Bt,
                                                        float* __restrict__ C,
                                                        const float* __restrict__ bias,
                                                        int M, int N, int K) {
  __shared__ __align__(16) char lds[2 * 65536];  // buf = A 32KB + B 32KB
  const int tid = threadIdx.x;
  const int l = tid & 63;
  const int w = tid >> 6;
  const int wr = w >> 2;
  const int wc = w & 3;
  const int lr = l & 15;
  const int q = l >> 4;

  const int cpx = (int)gridDim.x >> 3;
  const int swzb = ((int)blockIdx.x & 7) * cpx + ((int)blockIdx.x >> 3);
  const int nNT = N >> 8;
  const int mt = swzb / nNT;
  const int nt = swzb % nNT;
  const int m0 = mt << 8;
  const int n0 = nt << 8;

  const f16_t* Apanel = A + (size_t)m0 * K;
  const f16_t* Bpanel = Bt + (size_t)n0 * K;

  const int x7 = lr & 7;  // read-side XOR key (== lds row & 7 for all frag reads)

  f32x4 acc[8][4];
#pragma unroll
  for (int m = 0; m < 8; ++m)
#pragma unroll
    for (int n = 0; n < 4; ++n) acc[m][n] = f32x4{0.f, 0.f, 0.f, 0.f};

  const int nT = K >> 6;  // 16

  f16x8 a0[4][2], a1[4][2], b0[2][2], b1[2][2];

  // a-frag byte offset: [(mh*2+wr)*8192] + (mm*16+lr)*128 + ((kk*4+q)^x7)*16
#define AREAD(DST, MH, BUF)                                                     \
  do {                                                                          \
    const char* p_ = (BUF) + (((MH)*2 + wr) << 13);                             \
    _Pragma("unroll") for (int mm = 0; mm < 4; ++mm)                            \
      _Pragma("unroll") for (int kk = 0; kk < 2; ++kk)                          \
        DST[mm][kk] = *(const f16x8*)(p_ + ((mm * 16 + lr) << 7) +              \
                                      ((((kk << 2) + q) ^ x7) << 4));           \
  } while (0)
  // b-frag byte offset: 32768 + ((np*4+wc)*4096) + (nn*16+lr)*128 + ((kk*4+q)^x7)*16
#define BREAD(DST, NP, BUF)                                                     \
  do {                                                                          \
    const char* p_ = (BUF) + 32768 + ((((NP) << 2) + wc) << 12);                \
    _Pragma("unroll") for (int nn = 0; nn < 2; ++nn)                            \
      _Pragma("unroll") for (int kk = 0; kk < 2; ++kk)                          \
        DST[nn][kk] = *(const f16x8*)(p_ + ((nn * 16 + lr) << 7) +              \
                                      ((((kk << 2) + q) ^ x7) << 4));           \
  } while (0)
#define PH_MFMA(MB, AR, BR, NPB)                                                \
  do {                                                                          \
    __builtin_amdgcn_s_setprio(1);                                              \
    _Pragma("unroll") for (int mm = 0; mm < 4; ++mm)                            \
      _Pragma("unroll") for (int nn = 0; nn < 2; ++nn) {                        \
        acc[(MB) + mm][(NPB)*2 + nn] = __builtin_amdgcn_mfma_f32_16x16x32_f16(  \
            AR[mm][0], BR[nn][0], acc[(MB) + mm][(NPB)*2 + nn], 0, 0, 0);       \
        acc[(MB) + mm][(NPB)*2 + nn] = __builtin_amdgcn_mfma_f32_16x16x32_f16(  \
            AR[mm][1], BR[nn][1], acc[(MB) + mm][(NPB)*2 + nn], 0, 0, 0);       \
      }                                                                         \
    __builtin_amdgcn_s_setprio(0);                                              \
  } while (0)

  // prologue: tile 0 -> buf0 in canonical order; establish invariant
  stageA64(Apanel, K, 0, 0, lds, w, l);
  stageB64(Bpanel, K, 0, 0, lds + 32768, w, l);
  stageA64(Apanel, K, 0, 1, lds, w, l);
  stageB64(Bpanel, K, 0, 1, lds + 32768, w, l);
  stageA64(Apanel, K, 0, 2, lds, w, l);
  stageB64(Bpanel, K, 0, 2, lds + 32768, w, l);
  stageA64(Apanel, K, 0, 3, lds, w, l);
  stageB64(Bpanel, K, 0, 3, lds + 32768, w, l);
  VMCNT(4);  // A0,B0,A1,B1 landed; [A2,B2,A3,B3] in flight
  BARX();

  for (int tt = 0; tt < nT; ++tt) {
    char* cur = lds + (tt & 1) * 65536;
    char* nxtA = lds + ((tt + 1) & 1) * 65536;
    char* nxtB = nxtA + 32768;
    const int ktn = (tt + 1) < nT ? (tt + 1) : (nT - 1);

    // ---- phase 0 ----
    AREAD(a0, 0, cur);
    BREAD(b0, 0, cur);
    stageA64(Apanel, K, ktn, 0, nxtA, w, l);
    stageB64(Bpanel, K, ktn, 0, nxtB, w, l);
    VMCNT(2);  // certify [A2,B2,A3,B3] (this tile's ph1/ph2 frag data)
    BARX();
    LGKM0();
    SCHEDB0();
    PH_MFMA(0, a0, b0, 0);
    BARX();

    // ---- phase 1 ----
    BREAD(b1, 1, cur);
    stageA64(Apanel, K, ktn, 1, nxtA, w, l);
    stageB64(Bpanel, K, ktn, 1, nxtB, w, l);
    BARX();
    LGKM0();
    SCHEDB0();
    PH_MFMA(0, a0, b1, 1);
    BARX();

    // ---- phase 2 ----
    AREAD(a1, 1, cur);
    stageA64(Apanel, K, ktn, 2, nxtA, w, l);
    stageB64(Bpanel, K, ktn, 2, nxtB, w, l);
    BARX();
    LGKM0();
    SCHEDB0();
    PH_MFMA(4, a1, b0, 0);
    BARX();

    // ---- phase 3 ----
    stageA64(Apanel, K, ktn, 3, nxtA, w, l);
    stageB64(Bpanel, K, ktn, 3, nxtB, w, l);
    BARX();
    PH_MFMA(4, a1, b1, 1);
    VMCNT(4);  // next tile's ph0 needs (A0',B0',A1',B1') landed; invariant kept
    BARX();
  }
#undef AREAD
#undef BREAD
#undef PH_MFMA

  // epilogue: C/D layout col = l&15, row = q*4 + j
  float bs[4];
#pragma unroll
  for (int n = 0; n < 4; ++n) bs[n] = bias[n0 + (wc << 6) + (n << 4) + lr];
#pragma unroll
  for (int m = 0; m < 8; ++m) {
    const int gm = m0 + (wr << 7) + (m << 4) + (q << 2);
#pragma unroll
    for (int j = 0; j < 4; ++j) {
      float* Crow = C + (size_t)(gm + j) * N + n0 + (wc << 6) + lr;
#pragma unroll
      for (int n = 0; n < 4; ++n) Crow[n << 4] = acc[m][n][j] + bs[n];
    }
  }
}

// ---------------- launch ----------------

extern "C" void kernel_launch(void* const* d_in, const int* in_sizes, int n_in,
                              void* d_out, int out_size, void* d_ws, size_t ws_size,
                              hipStream_t stream) {
  const float* x = (const float*)d_in[0];    // [8,4096,1024]
  const float* Wv = (const float*)d_in[1];   // [1024,1024]
  const float* bv = (const float*)d_in[2];   // [1024]
  const float* Wo = (const float*)d_in[3];   // [1024,1024]
  const float* bo = (const float*)d_in[4];   // [1024]
  const float* nw = (const float*)d_in[5];   // [3]
  float* out = (float*)d_out;

  char* ws = (char*)d_ws;
  f16_t* WcT  = (f16_t*)(ws + (4u << 20));     // 2 MB (WcT = Wo @ Wv, [e][c])
  float* bc   = (float*)(ws + (6u << 20));     // 4 KB
  f16_t* Xavg = (f16_t*)(ws + (8u << 20));     // 64 MB

  // 1) parallel prep: WcT (first, hidden) || bconst || xavg
  prep_fused_kernel<<<dim3(5184), dim3(256), 0, stream>>>(
      x, Wo, Wv, bv, bo, nw, in_sizes[5], Xavg, WcT, bc);
  // 2) out[r][e] = sum_c Xavg[r][c] * WcT[e][c] + bc[e]
  gemm8p_kernel<<<dim3(512), dim3(512), 0, stream>>>(
      Xavg, WcT, out, bc, 32768, 1024, 1024);
}

// Round 16
// 139.869 us; speedup vs baseline: 1.2686x; 1.0079x over previous
//
#include <hip/hip_runtime.h>
#include <stdint.h>
#include <stddef.h>

typedef _Float16 f16_t;
typedef _Float16 f16x4 __attribute__((ext_vector_type(4)));
typedef _Float16 f16x8 __attribute__((ext_vector_type(8)));
typedef float f32x4 __attribute__((ext_vector_type(4)));
typedef float f32x8 __attribute__((ext_vector_type(8)));

#define AS_G __attribute__((address_space(1)))
#define AS_L __attribute__((address_space(3)))

__device__ __forceinline__ void gload_lds16(const void* g, void* l) {
  __builtin_amdgcn_global_load_lds((AS_G void*)g, (AS_L void*)l, 16, 0, 0);
}

#define FENCE() asm volatile("" ::: "memory")
#define BARX()                            \
  do {                                    \
    FENCE();                              \
    __builtin_amdgcn_s_barrier();         \
    FENCE();                              \
  } while (0)
#define VMCNT(n) asm volatile("s_waitcnt vmcnt(" #n ")" ::: "memory")
#define LGKM0() asm volatile("s_waitcnt lgkmcnt(0)" ::: "memory")
#if defined(__HIP_DEVICE_COMPILE__)
#define SCHEDB0() __builtin_amdgcn_sched_barrier(0)
#else
#define SCHEDB0()
#endif

// ---------------- dispatch 1: fully-parallel prep ----------------
// blocks [0,64): WcT from raw f32 (dispatched FIRST -> hidden under xavg flood);
// [64,1088): bconst; [1088,5184): xavg 3-tap with f16x8 (16B) stores.

__global__ __launch_bounds__(256) void prep_fused_kernel(
    const float* __restrict__ X, const float* __restrict__ Wo,
    const float* __restrict__ Wv, const float* __restrict__ bv,
    const float* __restrict__ bo, const float* __restrict__ nw, int Kw,
    f16_t* __restrict__ Xavg, f16_t* __restrict__ WcT, float* __restrict__ bc) {
  __shared__ __align__(16) f16_t sA[128 * 32];
  __shared__ __align__(16) float sWvT[128 * 36];
  __shared__ float smem[256];
  const int b = blockIdx.x;
  const int tid = threadIdx.x;

  if (b < 64) {
    // ---- WcT[e][c] = sum_d Wo[e][d]*Wv[d][c], raw f32 inputs, f16 out ----
    constexpr int K = 1024, NN = 1024;
    const int mt = b & 7, nt = b >> 3;
    const int m0 = mt << 7, n0 = nt << 7;
    const int l = tid & 63, w = tid >> 6;
    const int wr = w >> 1, wc = w & 1;
    const int q = l >> 4;
    const int ka = q << 3;
    const int ar = (wr << 6) + (l & 15);
    const int br = (wc << 6) + (l & 15);
    const int kS = tid >> 3;
    const int cS = (tid & 7) << 4;

    f32x4 acc[4][4];
#pragma unroll
    for (int i = 0; i < 4; ++i)
#pragma unroll
      for (int j = 0; j < 4; ++j) acc[i][j] = f32x4{0.f, 0.f, 0.f, 0.f};

    for (int kt = 0; kt < (K >> 5); ++kt) {
      const int kb = kt << 5;
#pragma unroll
      for (int i = 0; i < 2; ++i) {
        const int u = tid + i * 256;
        const int row = u >> 2, ch = u & 3;
        f32x8 v = *(const f32x8*)(Wo + (size_t)(m0 + row) * K + kb + ch * 8);
        f16x8 h;
#pragma unroll
        for (int e = 0; e < 8; ++e) h[e] = (f16_t)v[e];
        *(f16x8*)(sA + row * 32 + ch * 8) = h;
      }
#pragma unroll
      for (int j = 0; j < 4; ++j) {
        f32x4 v = *(const f32x4*)(Wv + (size_t)(kb + kS) * NN + n0 + cS + 4 * j);
#pragma unroll
        for (int i = 0; i < 4; ++i) sWvT[(cS + 4 * j + i) * 36 + kS] = v[i];
      }
      __syncthreads();
      f16x8 af[4], bfr[4];
#pragma unroll
      for (int m = 0; m < 4; ++m) af[m] = *(const f16x8*)(sA + (ar + (m << 4)) * 32 + ka);
#pragma unroll
      for (int n = 0; n < 4; ++n) {
        f32x4 v0 = *(const f32x4*)(sWvT + (br + (n << 4)) * 36 + ka);
        f32x4 v1 = *(const f32x4*)(sWvT + (br + (n << 4)) * 36 + ka + 4);
#pragma unroll
        for (int e = 0; e < 4; ++e) {
          bfr[n][e] = (f16_t)v0[e];
          bfr[n][e + 4] = (f16_t)v1[e];
        }
      }
#pragma unroll
      for (int m = 0; m < 4; ++m)
#pragma unroll
        for (int n = 0; n < 4; ++n)
          acc[m][n] = __builtin_amdgcn_mfma_f32_16x16x32_f16(af[m], bfr[n], acc[m][n], 0, 0, 0);
      __syncthreads();
    }

    const int orow = q << 2;
    const int ocol = l & 15;
#pragma unroll
    for (int n = 0; n < 4; ++n) {
      const int gn = n0 + (wc << 6) + (n << 4) + ocol;
#pragma unroll
      for (int m = 0; m < 4; ++m) {
        const int gm = m0 + (wr << 6) + (m << 4) + orow;
#pragma unroll
        for (int j = 0; j < 4; ++j)
          WcT[(size_t)(gm + j) * NN + gn] = (f16_t)acc[m][n][j];
      }
    }
  } else if (b < 1088) {
    // ---- bconst ----
    const int e = b - 64;
    float sw = 0.f;
    for (int k = 0; k < Kw; ++k) sw += nw[k];
    float p = 0.f;
    for (int d = tid; d < 1024; d += 256) p += Wo[(size_t)e * 1024 + d] * bv[d];
    smem[tid] = p;
    __syncthreads();
    for (int s = 128; s > 0; s >>= 1) {
      if (tid < s) smem[tid] += smem[tid + s];
      __syncthreads();
    }
    if (tid == 0) bc[e] = sw * smem[0] + bo[e];
  } else {
    // ---- xavg: 3-tap, 8 rows/block as 2 groups of 4 rows, f32x8 loads, f16x8 stores ----
    const int T = 4096, D = 1024;
    const int base = (b - 1088) * 8;
    const int bb = (base >> 12) << 12;   // batch start
    const int be = bb + T - 1;           // batch end (replicate boundary)
    const int half = tid >> 7;           // 0/1 -> rows [base+4h, base+4h+4)
    const int r0 = base + (half << 2);
    const int col = (tid & 127) << 3;    // 8-f32 column chunk
    const float w0 = nw[0], w1 = nw[1], w2 = nw[2];
    const float* xb = X + (size_t)r0 * D + col;
    f32x8 pp = *(const f32x8*)(xb + ((r0 == bb) ? 0 : -D));  // row r0-1 (clamped)
    f32x8 pc = *(const f32x8*)(xb);                          // row r0
    f16_t* ob = Xavg + (size_t)r0 * D + col;
#pragma unroll
    for (int g = 0; g < 4; ++g) {
      f32x8 pn;
      if (r0 + g == be) pn = pc;                              // replicate at batch end
      else pn = *(const f32x8*)(xb + (size_t)(g + 1) * D);
      f32x8 y = w0 * pp + w1 * pc + w2 * pn;
      f16x8 o;
#pragma unroll
      for (int e = 0; e < 8; ++e) o[e] = (f16_t)y[e];
      *(f16x8*)(ob + (size_t)g * D) = o;
      pp = pc;
      pc = pn;
    }
  }
}

// ---------------- dispatch 2: 256^2 GEMM, 8-phase + counted vmcnt (r15 best, frozen) ----------------
// out[M][N] = A[M][K]*Bt[N][K]^T + bias. 8 waves (2Mx4N), 16x16x32 MFMA, BK=64.
// See r15 notes: 2x64KB dbuf; phases ph0..ph3 with 16 MFMA each; stages spread
// 2/phase in frag-prefix order; VMCNT(2) at ph0, VMCNT(4) at ph3 (never 0);
// XOR row swizzle both sides.

__device__ __forceinline__ void stageA64(const f16_t* __restrict__ Ap, int K, int kt,
                                         int c, char* bufA, int w, int l) {
  const int f = w * 64 + l;
  const int sub = f >> 3, ch = f & 7;
  const int grow = ((c & 1) << 7) + ((c >> 1) << 6) + sub;
  const int gcol = (kt << 6) + ((ch ^ (sub & 7)) << 3);
  gload_lds16(Ap + (size_t)grow * K + gcol, bufA + c * 8192 + w * 1024);
}

__device__ __forceinline__ void stageB64(const f16_t* __restrict__ Bp, int K, int kt,
                                         int c, char* bufB, int w, int l) {
  const int f = w * 64 + l;
  const int rr = f >> 3, ch = f & 7;
  const int wc = ((c & 1) << 1) + (rr >> 5);
  const int sub = rr & 31;
  const int grow = (wc << 6) + ((c >> 1) << 5) + sub;
  const int gcol = (kt << 6) + ((ch ^ (sub & 7)) << 3);
  gload_lds16(Bp + (size_t)grow * K + gcol, bufB + c * 8192 + w * 1024);
}

__global__ __launch_bounds__(512, 2) void gemm8p_kernel(const f16_t* __restrict__ A,
                                                        const f16_t* __restrict__ Bt,
                                                        float* __restrict__ C,
                                                        const float* __restrict__ bias,
                                                        int M, int N, int K) {
  __shared__ __align__(16) char lds[2 * 65536];
  const int tid = threadIdx.x;
  const int l = tid & 63;
  const int w = tid >> 6;
  const int wr = w >> 2;
  const int wc = w & 3;
  const int lr = l & 15;
  const int q = l >> 4;

  const int cpx = (int)gridDim.x >> 3;
  const int swzb = ((int)blockIdx.x & 7) * cpx + ((int)blockIdx.x >> 3);
  const int nNT = N >> 8;
  const int mt = swzb / nNT;
  const int nt = swzb % nNT;
  const int m0 = mt << 8;
  const int n0 = nt << 8;

  const f16_t* Apanel = A + (size_t)m0 * K;
  const f16_t* Bpanel = Bt + (size_t)n0 * K;

  const int x7 = lr & 7;

  f32x4 acc[8][4];
#pragma unroll
  for (int m = 0; m < 8; ++m)
#pragma unroll
    for (int n = 0; n < 4; ++n) acc[m][n] = f32x4{0.f, 0.f, 0.f, 0.f};

  const int nT = K >> 6;

  f16x8 a0[4][2], a1[4][2], b0[2][2], b1[2][2];

#define AREAD(DST, MH, BUF)                                                     \
  do {                                                                          \
    const char* p_ = (BUF) + (((MH)*2 + wr) << 13);                             \
    _Pragma("unroll") for (int mm = 0; mm < 4; ++mm)                            \
      _Pragma("unroll") for (int kk = 0; kk < 2; ++kk)                          \
        DST[mm][kk] = *(const f16x8*)(p_ + ((mm * 16 + lr) << 7) +              \
                                      ((((kk << 2) + q) ^ x7) << 4));           \
  } while (0)
#define BREAD(DST, NP, BUF)                                                     \
  do {                                                                          \
    const char* p_ = (BUF) + 32768 + ((((NP) << 2) + wc) << 12);                \
    _Pragma("unroll") for (int nn = 0; nn < 2; ++nn)                            \
      _Pragma("unroll") for (int kk = 0; kk < 2; ++kk)                          \
        DST[nn][kk] = *(const f16x8*)(p_ + ((nn * 16 + lr) << 7) +              \
                                      ((((kk << 2) + q) ^ x7) << 4));           \
  } while (0)
#define PH_MFMA(MB, AR, BR, NPB)                                                \
  do {                                                                          \
    __builtin_amdgcn_s_setprio(1);                                              \
    _Pragma("unroll") for (int mm = 0; mm < 4; ++mm)                            \
      _Pragma("unroll") for (int nn = 0; nn < 2; ++nn) {                        \
        acc[(MB) + mm][(NPB)*2 + nn] = __builtin_amdgcn_mfma_f32_16x16x32_f16(  \
            AR[mm][0], BR[nn][0], acc[(MB) + mm][(NPB)*2 + nn], 0, 0, 0);       \
        acc[(MB) + mm][(NPB)*2 + nn] = __builtin_amdgcn_mfma_f32_16x16x32_f16(  \
            AR[mm][1], BR[nn][1], acc[(MB) + mm][(NPB)*2 + nn], 0, 0, 0);       \
      }                                                                         \
    __builtin_amdgcn_s_setprio(0);                                              \
  } while (0)

  // prologue: tile 0 -> buf0 in canonical order; establish invariant
  stageA64(Apanel, K, 0, 0, lds, w, l);
  stageB64(Bpanel, K, 0, 0, lds + 32768, w, l);
  stageA64(Apanel, K, 0, 1, lds, w, l);
  stageB64(Bpanel, K, 0, 1, lds + 32768, w, l);
  stageA64(Apanel, K, 0, 2, lds, w, l);
  stageB64(Bpanel, K, 0, 2, lds + 32768, w, l);
  stageA64(Apanel, K, 0, 3, lds, w, l);
  stageB64(Bpanel, K, 0, 3, lds + 32768, w, l);
  VMCNT(4);
  BARX();

  for (int tt = 0; tt < nT; ++tt) {
    char* cur = lds + (tt & 1) * 65536;
    char* nxtA = lds + ((tt + 1) & 1) * 65536;
    char* nxtB = nxtA + 32768;
    const int ktn = (tt + 1) < nT ? (tt + 1) : (nT - 1);

    // ---- phase 0 ----
    AREAD(a0, 0, cur);
    BREAD(b0, 0, cur);
    stageA64(Apanel, K, ktn, 0, nxtA, w, l);
    stageB64(Bpanel, K, ktn, 0, nxtB, w, l);
    VMCNT(2);
    BARX();
    LGKM0();
    SCHEDB0();
    PH_MFMA(0, a0, b0, 0);
    BARX();

    // ---- phase 1 ----
    BREAD(b1, 1, cur);
    stageA64(Apanel, K, ktn, 1, nxtA, w, l);
    stageB64(Bpanel, K, ktn, 1, nxtB, w, l);
    BARX();
    LGKM0();
    SCHEDB0();
    PH_MFMA(0, a0, b1, 1);
    BARX();

    // ---- phase 2 ----
    AREAD(a1, 1, cur);
    stageA64(Apanel, K, ktn, 2, nxtA, w, l);
    stageB64(Bpanel, K, ktn, 2, nxtB, w, l);
    BARX();
    LGKM0();
    SCHEDB0();
    PH_MFMA(4, a1, b0, 0);
    BARX();

    // ---- phase 3 ----
    stageA64(Apanel, K, ktn, 3, nxtA, w, l);
    stageB64(Bpanel, K, ktn, 3, nxtB, w, l);
    BARX();
    PH_MFMA(4, a1, b1, 1);
    VMCNT(4);
    BARX();
  }
#undef AREAD
#undef BREAD
#undef PH_MFMA

  // epilogue: C/D layout col = l&15, row = q*4 + j
  float bs[4];
#pragma unroll
  for (int n = 0; n < 4; ++n) bs[n] = bias[n0 + (wc << 6) + (n << 4) + lr];
#pragma unroll
  for (int m = 0; m < 8; ++m) {
    const int gm = m0 + (wr << 7) + (m << 4) + (q << 2);
#pragma unroll
    for (int j = 0; j < 4; ++j) {
      float* Crow = C + (size_t)(gm + j) * N + n0 + (wc << 6) + lr;
#pragma unroll
      for (int n = 0; n < 4; ++n) Crow[n << 4] = acc[m][n][j] + bs[n];
    }
  }
}

// ---------------- launch ----------------

extern "C" void kernel_launch(void* const* d_in, const int* in_sizes, int n_in,
                              void* d_out, int out_size, void* d_ws, size_t ws_size,
                              hipStream_t stream) {
  const float* x = (const float*)d_in[0];    // [8,4096,1024]
  const float* Wv = (const float*)d_in[1];   // [1024,1024]
  const float* bv = (const float*)d_in[2];   // [1024]
  const float* Wo = (const float*)d_in[3];   // [1024,1024]
  const float* bo = (const float*)d_in[4];   // [1024]
  const float* nw = (const float*)d_in[5];   // [3]
  float* out = (float*)d_out;

  char* ws = (char*)d_ws;
  f16_t* WcT  = (f16_t*)(ws + (4u << 20));     // 2 MB (WcT = Wo @ Wv, [e][c])
  float* bc   = (float*)(ws + (6u << 20));     // 4 KB
  f16_t* Xavg = (f16_t*)(ws + (8u << 20));     // 64 MB

  // 1) parallel prep: WcT (first, hidden) || bconst || xavg (f16x8 stores)
  prep_fused_kernel<<<dim3(5184), dim3(256), 0, stream>>>(
      x, Wo, Wv, bv, bo, nw, in_sizes[5], Xavg, WcT, bc);
  // 2) out[r][e] = sum_c Xavg[r][c] * WcT[e][c] + bc[e]
  gemm8p_kernel<<<dim3(512), dim3(512), 0, stream>>>(
      Xavg, WcT, out, bc, 32768, 1024, 1024);
}

// Round 17
// 133.898 us; speedup vs baseline: 1.3252x; 1.0446x over previous
//
#include <hip/hip_runtime.h>
#include <stdint.h>
#include <stddef.h>

typedef _Float16 f16_t;
typedef _Float16 f16x4 __attribute__((ext_vector_type(4)));
typedef _Float16 f16x8 __attribute__((ext_vector_type(8)));
typedef float f32x4 __attribute__((ext_vector_type(4)));
typedef float f32x8 __attribute__((ext_vector_type(8)));

#define AS_G __attribute__((address_space(1)))
#define AS_L __attribute__((address_space(3)))

__device__ __forceinline__ void gload_lds16(const void* g, void* l) {
  __builtin_amdgcn_global_load_lds((AS_G void*)g, (AS_L void*)l, 16, 0, 0);
}

#define FENCE() asm volatile("" ::: "memory")
#define BARX()                            \
  do {                                    \
    FENCE();                              \
    __builtin_amdgcn_s_barrier();         \
    FENCE();                              \
  } while (0)
#define VMCNT(n) asm volatile("s_waitcnt vmcnt(" #n ")" ::: "memory")
#define LGKM0() asm volatile("s_waitcnt lgkmcnt(0)" ::: "memory")
#if defined(__HIP_DEVICE_COMPILE__)
#define SCHEDB0() __builtin_amdgcn_sched_barrier(0)
#else
#define SCHEDB0()
#endif

// ---------------- dispatch 1: weight prep (small, memory-bound) ----------------
// blocks [0,1024): Wo f32->f16 cvt; [1024,2048): Wv transpose+cvt -> WvT; [2048,3072): bconst

__global__ __launch_bounds__(256) void wprep_kernel(
    const float* __restrict__ Wo, const float* __restrict__ Wv,
    const float* __restrict__ bv, const float* __restrict__ bo,
    const float* __restrict__ nw, int Kw,
    f16_t* __restrict__ Wo_h, f16_t* __restrict__ WvT, float* __restrict__ bc) {
  __shared__ float smem[32 * 33];
  const int b = blockIdx.x;
  const int t = threadIdx.x;
  if (b < 1024) {
    const int i = b * 256 + t;
    f32x4 v = ((const f32x4*)Wo)[i];
    f16x4 o;
    o.x = (f16_t)v.x; o.y = (f16_t)v.y; o.z = (f16_t)v.z; o.w = (f16_t)v.w;
    ((f16x4*)Wo_h)[i] = o;
  } else if (b < 2048) {
    const int i = b - 1024;
    const int bx = i & 31, by = i >> 5;
    const int tx = t & 31, ty = t >> 5;  // 32 x 8
#pragma unroll
    for (int k = 0; k < 32; k += 8)
      smem[(ty + k) * 33 + tx] = Wv[(size_t)(by * 32 + ty + k) * 1024 + bx * 32 + tx];
    __syncthreads();
#pragma unroll
    for (int k = 0; k < 32; k += 8)
      WvT[(size_t)(bx * 32 + ty + k) * 1024 + by * 32 + tx] = (f16_t)smem[tx * 33 + ty + k];
  } else {
    const int e = b - 2048;
    float sw = 0.f;
    for (int k = 0; k < Kw; ++k) sw += nw[k];
    float p = 0.f;
    for (int d = t; d < 1024; d += 256) p += Wo[(size_t)e * 1024 + d] * bv[d];
    smem[t] = p;
    __syncthreads();
    for (int s = 128; s > 0; s >>= 1) {
      if (t < s) smem[t] += smem[t + s];
      __syncthreads();
    }
    if (t == 0) bc[e] = sw * smem[0] + bo[e];
  }
}

// ---------------- dispatch 2: WcT fast-path GEMM (hidden) || xavg 32-row ----------------
// blocks [0,64): WcT[e][c] = sum_d Wo_h[e][d]*WvT[c][d]  (128^2 MFMA, gload_lds both ops)
// blocks [64,1088): xavg 3-tap, 32 rows/block (2 groups x 16 rolling rows),
//                   f32x8 loads / f16x8 stores; read ratio 36/32 = 1.125x.

__global__ __launch_bounds__(256) void xavg_wct_kernel(
    const float* __restrict__ X, const float* __restrict__ nw,
    const f16_t* __restrict__ Wo_h, const f16_t* __restrict__ WvT,
    f16_t* __restrict__ Xavg, f16_t* __restrict__ WcT) {
  __shared__ __align__(16) f16_t sAB[2 * 128 * 32];  // 16 KB (WcT branch only)
  const int b = blockIdx.x;
  const int tid = threadIdx.x;

  if (b < 64) {
    // ---- 128^2 MFMA GEMM, both operands f16 via gload_lds (r11-proven) ----
    constexpr int K = 1024, NN = 1024;
    f16_t* sA = sAB;
    f16_t* sB = sAB + 128 * 32;
    const int l = tid & 63;
    const int w = tid >> 6;
    const int wr = w >> 1;
    const int wc = w & 1;
    const int mt = b & 7;
    const int nt = b >> 3;
    const int m0 = mt << 7;
    const int n0 = nt << 7;

    const int srow = (w << 4) + (l >> 2);
    const int scol = (l & 3) << 3;
    const size_t aoff0 = (size_t)(m0 + srow) * K + scol;
    const size_t boff0 = (size_t)(n0 + srow) * K + scol;
    f16_t* ldsA = sA + (w << 9);
    f16_t* ldsB = sB + (w << 9);

    f32x4 acc[4][4];
#pragma unroll
    for (int i = 0; i < 4; ++i)
#pragma unroll
      for (int j = 0; j < 4; ++j) acc[i][j] = f32x4{0.f, 0.f, 0.f, 0.f};

    const int ka = (l >> 4) << 3;
    const int ar = (wr << 6) + (l & 15);
    const int br = (wc << 6) + (l & 15);

    for (int kt = 0; kt < (K >> 5); ++kt) {
      const int kb = kt << 5;
      gload_lds16(Wo_h + aoff0 + kb, ldsA);
      gload_lds16(Wo_h + aoff0 + ((size_t)K << 6) + kb, ldsA + 2048);
      gload_lds16(WvT + boff0 + kb, ldsB);
      gload_lds16(WvT + boff0 + ((size_t)K << 6) + kb, ldsB + 2048);
      __syncthreads();
      f16x8 af[4], bfr[4];
#pragma unroll
      for (int m = 0; m < 4; ++m) af[m] = *(const f16x8*)(sA + ((ar + (m << 4)) << 5) + ka);
#pragma unroll
      for (int n = 0; n < 4; ++n) bfr[n] = *(const f16x8*)(sB + ((br + (n << 4)) << 5) + ka);
#pragma unroll
      for (int m = 0; m < 4; ++m)
#pragma unroll
        for (int n = 0; n < 4; ++n)
          acc[m][n] = __builtin_amdgcn_mfma_f32_16x16x32_f16(af[m], bfr[n], acc[m][n], 0, 0, 0);
      __syncthreads();
    }

    const int orow = (l >> 4) << 2;
    const int ocol = l & 15;
#pragma unroll
    for (int n = 0; n < 4; ++n) {
      const int gn = n0 + (wc << 6) + (n << 4) + ocol;
#pragma unroll
      for (int m = 0; m < 4; ++m) {
        const int gm = m0 + (wr << 6) + (m << 4) + orow;
#pragma unroll
        for (int j = 0; j < 4; ++j)
          WcT[(size_t)(gm + j) * NN + gn] = (f16_t)acc[m][n][j];
      }
    }
  } else {
    // ---- xavg: 32 rows/block; 2 groups of 16 rolling rows; never straddles batch ----
    const int T = 4096, D = 1024;
    const int R0 = (b - 64) * 32;
    const int half = tid >> 7;           // 0/1 -> rows [R0+16h, R0+16h+16)
    const int r0 = R0 + (half << 4);
    const int bb = (r0 >> 12) << 12;     // batch start
    const int be = bb + T - 1;           // batch end
    const int col = (tid & 127) << 3;    // 8-f32 column chunk
    const float w0 = nw[0], w1 = nw[1], w2 = nw[2];
    const float* xb = X + (size_t)r0 * D + col;
    f32x8 pp = *(const f32x8*)(xb + ((r0 == bb) ? 0 : -D));
    f32x8 pc = *(const f32x8*)(xb);
    f16_t* ob = Xavg + (size_t)r0 * D + col;
#pragma unroll
    for (int g = 0; g < 16; ++g) {
      f32x8 pn;
      if (r0 + g == be) pn = pc;
      else pn = *(const f32x8*)(xb + (size_t)(g + 1) * D);
      f32x8 y = w0 * pp + w1 * pc + w2 * pn;
      f16x8 o;
#pragma unroll
      for (int e = 0; e < 8; ++e) o[e] = (f16_t)y[e];
      *(f16x8*)(ob + (size_t)g * D) = o;
      pp = pc;
      pc = pn;
    }
  }
}

// ---------------- dispatch 3: 256^2 GEMM, 8-phase + counted vmcnt (r15 frozen) ----------------

__device__ __forceinline__ void stageA64(const f16_t* __restrict__ Ap, int K, int kt,
                                         int c, char* bufA, int w, int l) {
  const int f = w * 64 + l;
  const int sub = f >> 3, ch = f & 7;
  const int grow = ((c & 1) << 7) + ((c >> 1) << 6) + sub;
  const int gcol = (kt << 6) + ((ch ^ (sub & 7)) << 3);
  gload_lds16(Ap + (size_t)grow * K + gcol, bufA + c * 8192 + w * 1024);
}

__device__ __forceinline__ void stageB64(const f16_t* __restrict__ Bp, int K, int kt,
                                         int c, char* bufB, int w, int l) {
  const int f = w * 64 + l;
  const int rr = f >> 3, ch = f & 7;
  const int wc = ((c & 1) << 1) + (rr >> 5);
  const int sub = rr & 31;
  const int grow = (wc << 6) + ((c >> 1) << 5) + sub;
  const int gcol = (kt << 6) + ((ch ^ (sub & 7)) << 3);
  gload_lds16(Bp + (size_t)grow * K + gcol, bufB + c * 8192 + w * 1024);
}

__global__ __launch_bounds__(512, 2) void gemm8p_kernel(const f16_t* __restrict__ A,
                                                        const f16_t* __restrict__ Bt,
                                                        float* __restrict__ C,
                                                        const float* __restrict__ bias,
                                                        int M, int N, int K) {
  __shared__ __align__(16) char lds[2 * 65536];
  const int tid = threadIdx.x;
  const int l = tid & 63;
  const int w = tid >> 6;
  const int wr = w >> 2;
  const int wc = w & 3;
  const int lr = l & 15;
  const int q = l >> 4;

  const int cpx = (int)gridDim.x >> 3;
  const int swzb = ((int)blockIdx.x & 7) * cpx + ((int)blockIdx.x >> 3);
  const int nNT = N >> 8;
  const int mt = swzb / nNT;
  const int nt = swzb % nNT;
  const int m0 = mt << 8;
  const int n0 = nt << 8;

  const f16_t* Apanel = A + (size_t)m0 * K;
  const f16_t* Bpanel = Bt + (size_t)n0 * K;

  const int x7 = lr & 7;

  f32x4 acc[8][4];
#pragma unroll
  for (int m = 0; m < 8; ++m)
#pragma unroll
    for (int n = 0; n < 4; ++n) acc[m][n] = f32x4{0.f, 0.f, 0.f, 0.f};

  const int nT = K >> 6;

  f16x8 a0[4][2], a1[4][2], b0[2][2], b1[2][2];

#define AREAD(DST, MH, BUF)                                                     \
  do {                                                                          \
    const char* p_ = (BUF) + (((MH)*2 + wr) << 13);                             \
    _Pragma("unroll") for (int mm = 0; mm < 4; ++mm)                            \
      _Pragma("unroll") for (int kk = 0; kk < 2; ++kk)                          \
        DST[mm][kk] = *(const f16x8*)(p_ + ((mm * 16 + lr) << 7) +              \
                                      ((((kk << 2) + q) ^ x7) << 4));           \
  } while (0)
#define BREAD(DST, NP, BUF)                                                     \
  do {                                                                          \
    const char* p_ = (BUF) + 32768 + ((((NP) << 2) + wc) << 12);                \
    _Pragma("unroll") for (int nn = 0; nn < 2; ++nn)                            \
      _Pragma("unroll") for (int kk = 0; kk < 2; ++kk)                          \
        DST[nn][kk] = *(const f16x8*)(p_ + ((nn * 16 + lr) << 7) +              \
                                      ((((kk << 2) + q) ^ x7) << 4));           \
  } while (0)
#define PH_MFMA(MB, AR, BR, NPB)                                                \
  do {                                                                          \
    __builtin_amdgcn_s_setprio(1);                                              \
    _Pragma("unroll") for (int mm = 0; mm < 4; ++mm)                            \
      _Pragma("unroll") for (int nn = 0; nn < 2; ++nn) {                        \
        acc[(MB) + mm][(NPB)*2 + nn] = __builtin_amdgcn_mfma_f32_16x16x32_f16(  \
            AR[mm][0], BR[nn][0], acc[(MB) + mm][(NPB)*2 + nn], 0, 0, 0);       \
        acc[(MB) + mm][(NPB)*2 + nn] = __builtin_amdgcn_mfma_f32_16x16x32_f16(  \
            AR[mm][1], BR[nn][1], acc[(MB) + mm][(NPB)*2 + nn], 0, 0, 0);       \
      }                                                                         \
    __builtin_amdgcn_s_setprio(0);                                              \
  } while (0)

  stageA64(Apanel, K, 0, 0, lds, w, l);
  stageB64(Bpanel, K, 0, 0, lds + 32768, w, l);
  stageA64(Apanel, K, 0, 1, lds, w, l);
  stageB64(Bpanel, K, 0, 1, lds + 32768, w, l);
  stageA64(Apanel, K, 0, 2, lds, w, l);
  stageB64(Bpanel, K, 0, 2, lds + 32768, w, l);
  stageA64(Apanel, K, 0, 3, lds, w, l);
  stageB64(Bpanel, K, 0, 3, lds + 32768, w, l);
  VMCNT(4);
  BARX();

  for (int tt = 0; tt < nT; ++tt) {
    char* cur = lds + (tt & 1) * 65536;
    char* nxtA = lds + ((tt + 1) & 1) * 65536;
    char* nxtB = nxtA + 32768;
    const int ktn = (tt + 1) < nT ? (tt + 1) : (nT - 1);

    // ---- phase 0 ----
    AREAD(a0, 0, cur);
    BREAD(b0, 0, cur);
    stageA64(Apanel, K, ktn, 0, nxtA, w, l);
    stageB64(Bpanel, K, ktn, 0, nxtB, w, l);
    VMCNT(2);
    BARX();
    LGKM0();
    SCHEDB0();
    PH_MFMA(0, a0, b0, 0);
    BARX();

    // ---- phase 1 ----
    BREAD(b1, 1, cur);
    stageA64(Apanel, K, ktn, 1, nxtA, w, l);
    stageB64(Bpanel, K, ktn, 1, nxtB, w, l);
    BARX();
    LGKM0();
    SCHEDB0();
    PH_MFMA(0, a0, b1, 1);
    BARX();

    // ---- phase 2 ----
    AREAD(a1, 1, cur);
    stageA64(Apanel, K, ktn, 2, nxtA, w, l);
    stageB64(Bpanel, K, ktn, 2, nxtB, w, l);
    BARX();
    LGKM0();
    SCHEDB0();
    PH_MFMA(4, a1, b0, 0);
    BARX();

    // ---- phase 3 ----
    stageA64(Apanel, K, ktn, 3, nxtA, w, l);
    stageB64(Bpanel, K, ktn, 3, nxtB, w, l);
    BARX();
    PH_MFMA(4, a1, b1, 1);
    VMCNT(4);
    BARX();
  }
#undef AREAD
#undef BREAD
#undef PH_MFMA

  float bs[4];
#pragma unroll
  for (int n = 0; n < 4; ++n) bs[n] = bias[n0 + (wc << 6) + (n << 4) + lr];
#pragma unroll
  for (int m = 0; m < 8; ++m) {
    const int gm = m0 + (wr << 7) + (m << 4) + (q << 2);
#pragma unroll
    for (int j = 0; j < 4; ++j) {
      float* Crow = C + (size_t)(gm + j) * N + n0 + (wc << 6) + lr;
#pragma unroll
      for (int n = 0; n < 4; ++n) Crow[n << 4] = acc[m][n][j] + bs[n];
    }
  }
}

// ---------------- launch ----------------

extern "C" void kernel_launch(void* const* d_in, const int* in_sizes, int n_in,
                              void* d_out, int out_size, void* d_ws, size_t ws_size,
                              hipStream_t stream) {
  const float* x = (const float*)d_in[0];    // [8,4096,1024]
  const float* Wv = (const float*)d_in[1];   // [1024,1024]
  const float* bv = (const float*)d_in[2];   // [1024]
  const float* Wo = (const float*)d_in[3];   // [1024,1024]
  const float* bo = (const float*)d_in[4];   // [1024]
  const float* nw = (const float*)d_in[5];   // [3]
  float* out = (float*)d_out;

  char* ws = (char*)d_ws;
  f16_t* Wo_h = (f16_t*)(ws);                  // 2 MB
  f16_t* WvT  = (f16_t*)(ws + (2u << 20));     // 2 MB
  f16_t* WcT  = (f16_t*)(ws + (4u << 20));     // 2 MB (WcT = Wo @ Wv, [e][c])
  float* bc   = (float*)(ws + (6u << 20));     // 4 KB
  f16_t* Xavg = (f16_t*)(ws + (8u << 20));     // 64 MB

  // 1) weight prep: Wo cvt || WvT transpose || bconst (~16 MB, fast)
  wprep_kernel<<<dim3(3072), dim3(256), 0, stream>>>(
      Wo, Wv, bv, bo, nw, in_sizes[5], Wo_h, WvT, bc);
  // 2) WcT fast-path GEMM (blocks 0-63, hidden) || xavg 32-row (blocks 64-1087)
  xavg_wct_kernel<<<dim3(1088), dim3(256), 0, stream>>>(
      x, nw, Wo_h, WvT, Xavg, WcT);
  // 3) out[r][e] = sum_c Xavg[r][c] * WcT[e][c] + bc[e]
  gemm8p_kernel<<<dim3(512), dim3(512), 0, stream>>>(
      Xavg, WcT, out, bc, 32768, 1024, 1024);
}